// Round 20
// baseline (357.328 us; speedup 1.0000x reference)
//
#include <hip/hip_runtime.h>

#define KCODES 512
#define DIM 64
#define NB 32
#define NH 64
#define NW 64
#define NPTS (NB*NH*NW)     // 131072
#define HW (NH*NW)          // 4096

// ---- output layout (floats) ----
#define O_OUT  0
#define O_LOSS 8388608
#define O_IDX  8388609
#define O_EMB  8519681
#define O_M    8552449
#define O_MM   8585217

// ---- workspace layout (floats) ----
#define W_DM    0                   // 32768
#define W_CNT   32768               // 512
#define W_LOSS  33280               // 1
#define W_ZEND  33281               // zeroed extent: W_DM..W_LOSS
#define W_C     33282               // 512 codeword sq-norms (plain stores)
#define W_SUMM8 33794               // 8 per-wave partials of Sigma(ema_M)

#define XPAD 68

// cnorm + workspace zeroing + Sigma(ema_M) partials (r19 verbatim)
__global__ void cnorm_kernel(const float* __restrict__ emb,
                             const float* __restrict__ emaM,
                             float* __restrict__ ws) {
    int tid = blockIdx.x * blockDim.x + threadIdx.x;   // 0..511
    for (int i = tid; i < W_ZEND; i += 512) ws[i] = 0.f;
    int k = tid;
    float s = 0.f;
    #pragma unroll
    for (int d = 0; d < DIM; ++d) { float v = emb[k*DIM + d]; s += v*v; }
    ws[W_C + k] = s;
    float m = emaM[k];
    #pragma unroll
    for (int off = 32; off >= 1; off >>= 1) m += __shfl_down(m, off, 64);
    if ((tid & 63) == 0) ws[W_SUMM8 + (tid >> 6)] = m;
}

// assign v-final: r15's register-tiled GEMM with E read DIRECTLY from global
// (L1/L2-hot 128KB) instead of LDS staging. Splits operand streams across
// pipes: xf <- LDS (broadcast), ef <- VMEM/L1. Removes EL+cnT+ALL per-tile
// barriers; LDS 70->35KB -> 4 blocks/CU (16 waves, was 8). FMA chain order
// and scan order identical to r15 -> outputs bit-identical (absmax 50).
// Spill canary: WRITE_SIZE must stay ~0.5MB (r3 precedent: global-E SIMT
// loop compiled spill-free at VGPR 60; r11/r12's spills were MFMA frags).
__global__ __launch_bounds__(256, 4) void assign_kernel(
    const float* __restrict__ enc, const float* __restrict__ emb,
    float* __restrict__ out, float* __restrict__ ws)
{
    __shared__ float XL[128*XPAD];   // [point][d]  34.8KB
    __shared__ int   bestI[128];

    const int t  = threadIdx.x;
    const int tx = t & 15;
    const int ty = t >> 4;
    const int wv = t >> 6, w = t & 63;
    const int R0 = blockIdx.x * 2;

    #pragma unroll
    for (int r2 = 0; r2 < 2; ++r2) {
        int R = R0 + r2, b = R >> 6, h = R & 63;
        const float* base = enc + (size_t)b*64*HW + (size_t)h*64 + w;
        int p = r2*64 + w;
        #pragma unroll
        for (int it = 0; it < 4; ++it) {
            int d0 = (it*4 + wv)*4;
            float4 v = make_float4(base[(size_t)(d0+0)*HW], base[(size_t)(d0+1)*HW],
                                   base[(size_t)(d0+2)*HW], base[(size_t)(d0+3)*HW]);
            *(float4*)(&XL[p*XPAD + d0]) = v;
        }
    }
    __syncthreads();                 // X panel ready; no barriers after this

    float best[8]; int bidx[8];
    #pragma unroll
    for (int i = 0; i < 8; ++i) { best[i] = 3.402823466e38f; bidx[i] = 0; }

    for (int tile = 0; tile < 4; ++tile) {
        const float* etile = emb + (size_t)tile*128*64 + tx*64;  // row tx base

        float acc[8][8];
        #pragma unroll
        for (int i = 0; i < 8; ++i)
            #pragma unroll
            for (int j = 0; j < 8; ++j) acc[i][j] = 0.f;

        for (int c = 0; c < 16; ++c) {
            float4 xf[8], ef[8];
            #pragma unroll
            for (int i = 0; i < 8; ++i) {    // LDS broadcast reads (cheap)
                int p = 2*ty + (i&1) + 32*(i>>1);
                xf[i] = *(const float4*)(&XL[p*XPAD + c*4]);
            }
            #pragma unroll
            for (int j = 0; j < 8; ++j)      // global: row tx+16j, L1-hot
                ef[j] = *(const float4*)(etile + j*(16*64) + c*4);
            #pragma unroll
            for (int i = 0; i < 8; ++i)
                #pragma unroll
                for (int j = 0; j < 8; ++j) {
                    acc[i][j] = fmaf(xf[i].x, ef[j].x, acc[i][j]);
                    acc[i][j] = fmaf(xf[i].y, ef[j].y, acc[i][j]);
                    acc[i][j] = fmaf(xf[i].z, ef[j].z, acc[i][j]);
                    acc[i][j] = fmaf(xf[i].w, ef[j].w, acc[i][j]);
                }
        }

        #pragma unroll
        for (int j = 0; j < 8; ++j) {
            int k = tile*128 + tx + 16*j;
            float cn = ws[W_C + k];          // L1-hot scattered 4B
            #pragma unroll
            for (int i = 0; i < 8; ++i) {
                float s = cn - 2.f*acc[i][j];
                if (s < best[i]) { best[i] = s; bidx[i] = k; }  // k strictly
            }                                                   // increasing
        }
    }

    // cross-lane argmin over the 16 tx-lanes sharing each point
    #pragma unroll
    for (int i = 0; i < 8; ++i) {
        float b = best[i]; int kx = bidx[i];
        #pragma unroll
        for (int off = 1; off < 16; off <<= 1) {
            float ob = __shfl_xor(b, off, 64);
            int   ok = __shfl_xor(kx, off, 64);
            if (ob < b || (ob == b && ok < kx)) { b = ob; kx = ok; }
        }
        if (tx == 0) bestI[2*ty + (i&1) + 32*(i>>1)] = kx;
    }
    __syncthreads();
    if (t < 128) out[O_IDX + (size_t)R0*64 + t] = (float)bestI[t];
}

// scatter v3 (r15/r19 verbatim, best measured): role-split 16-wave kernel
// with per-wave dim rotation; loss computed inline in gather waves.
__global__ __launch_bounds__(1024, 1) void scatter_kernel(
    const float* __restrict__ enc, const float* __restrict__ emb,
    float* __restrict__ out, float* __restrict__ ws)
{
    __shared__ float dmL[KCODES][DIM+1];
    __shared__ float cntL[KCODES];
    __shared__ float redL[16];

    const int t  = threadIdx.x;
    const int w  = t & 63;
    const int wv = t >> 6;           // 0..15
    const int rw = wv & 7;           // row slot
    const int role = wv >> 3;        // 0: accumulate, 1: gather/store/loss
    const int pg = w >> 4, dl = w & 15;
    const int drot = (wv & 7) * 8;   // per-wave dim rotation (bijection)

    float* dmf = &dmL[0][0];
    for (int i = t; i < KCODES*(DIM+1); i += 1024) dmf[i] = 0.f;
    if (t < KCODES) cntL[t] = 0.f;
    __syncthreads();

    const int R = blockIdx.x * 8 + rw;
    const int b = R >> 6, h = R & 63;
    const float* base  = enc + (size_t)b*(64*HW) + (size_t)h*64;
    float*       obase = out + O_OUT + (size_t)b*(64*HW) + (size_t)h*64;

    const int bidx = (int)out[O_IDX + (size_t)R*64 + w];
    float lsum = 0.f;

    if (role == 0) {
        atomicAdd(&cntL[bidx], 1.0f);
        #pragma unroll
        for (int c = 0; c < 4; ++c) {
            #pragma unroll
            for (int jj = 0; jj < 16; ++jj) {
                int p  = jj*4 + pg;
                int kb = __shfl(bidx, p, 64);
                int d  = (c*16 + dl + drot) & 63;
                atomicAdd(&dmL[kb][d], base[(size_t)d*HW + p]);
            }
        }
    } else {
        #pragma unroll
        for (int c = 0; c < 4; ++c) {
            #pragma unroll
            for (int jj = 0; jj < 16; ++jj) {
                int p  = jj*4 + pg;
                int kb = __shfl(bidx, p, 64);
                int d  = (c*16 + dl + drot) & 63;
                float xv = base[(size_t)d*HW + p];
                float q  = emb[kb*64 + d];
                obase[(size_t)d*HW + p] = q;
                float df = q - xv;
                lsum = fmaf(df, df, lsum);
            }
        }
    }

    #pragma unroll
    for (int off = 32; off >= 1; off >>= 1) lsum += __shfl_down(lsum, off, 64);
    if (w == 0) redL[wv] = lsum;
    __syncthreads();
    if (t == 0) {
        float s = 0.f;
        #pragma unroll
        for (int v = 8; v < 16; ++v) s += redL[v];
        atomicAdd(&ws[W_LOSS], s);
    }

    // flush: wave wv owns 32 rows; lane = dim (coalesced 256B atomic runs)
    for (int k = wv*32; k < wv*32 + 32; ++k) {
        float c = cntL[k];
        if (c == 0.f) continue;
        atomicAdd(&ws[W_DM + k*64 + w], dmL[k][w]);
        if (w == 0) atomicAdd(&ws[W_CNT + k], c);
    }
}

// Single fully-parallel finalize; Ntot from the 8 deterministic partials.
__global__ void finalize_kernel(const float* __restrict__ emam,
                                const float* __restrict__ emaM,
                                float* __restrict__ out,
                                const float* __restrict__ ws)
{
    int i = blockIdx.x * blockDim.x + threadIdx.x;  // 0..32767
    int k = i >> 6;
    float summ = 0.f;
    #pragma unroll
    for (int v = 0; v < 8; ++v) summ += ws[W_SUMM8 + v];
    float Ntot = 0.99f * summ + 0.01f * (float)NPTS;
    float nM = 0.99f * emaM[k] + 0.01f * ws[W_CNT + k];
    float sm = (nM + 1e-5f) / (Ntot + 1e-5f * (float)KCODES) * Ntot;
    float nm = 0.99f * emam[i] + 0.01f * ws[W_DM + i];
    out[O_M + i] = nm;
    out[O_EMB + i] = nm / sm;
    if ((i & 63) == 0) out[O_MM + k] = sm;
    if (i == 0) out[O_LOSS] = 0.25f * ws[W_LOSS] / (float)((size_t)NPTS * DIM);
}

extern "C" void kernel_launch(void* const* d_in, const int* in_sizes, int n_in,
                              void* d_out, int out_size, void* d_ws, size_t ws_size,
                              hipStream_t stream)
{
    const float* enc  = (const float*)d_in[0];
    const float* emb  = (const float*)d_in[1];
    const float* emam = (const float*)d_in[2];
    const float* emaM = (const float*)d_in[3];
    float* out = (float*)d_out;
    float* ws  = (float*)d_ws;

    cnorm_kernel<<<2, 256, 0, stream>>>(emb, emaM, ws);   // zeroes ws too
    assign_kernel<<<NPTS/128, 256, 0, stream>>>(enc, emb, out, ws);   // 1024 blocks
    scatter_kernel<<<256, 1024, 0, stream>>>(enc, emb, out, ws);      // 8 rows/blk
    finalize_kernel<<<(KCODES*DIM)/256, 256, 0, stream>>>(emam, emaM, out, ws);
}

// Round 21
// 226.807 us; speedup vs baseline: 1.5755x; 1.5755x over previous
//
#include <hip/hip_runtime.h>

#define KCODES 512
#define DIM 64
#define NB 32
#define NH 64
#define NW 64
#define NPTS (NB*NH*NW)     // 131072
#define HW (NH*NW)          // 4096

// ---- output layout (floats) ----
#define O_OUT  0
#define O_LOSS 8388608
#define O_IDX  8388609
#define O_EMB  8519681
#define O_M    8552449
#define O_MM   8585217

// ---- workspace layout (floats) ----
#define W_DM    0                   // 32768
#define W_CNT   32768               // 512
#define W_LOSS  33280               // 1
#define W_ZEND  33281               // zeroed extent: W_DM..W_LOSS
#define W_C     33282               // 512 codeword sq-norms (plain stores)
#define W_SUMM8 33794               // 8 per-wave partials of Sigma(ema_M)

#define XPAD 68
#define EPAD 68

// cnorm + workspace zeroing (replaces hipMemsetAsync dispatch) + Sigma(ema_M)
// as 8 per-wave partial slots (plain stores, deterministic sum).
__global__ void cnorm_kernel(const float* __restrict__ emb,
                             const float* __restrict__ emaM,
                             float* __restrict__ ws) {
    int tid = blockIdx.x * blockDim.x + threadIdx.x;   // 0..511
    for (int i = tid; i < W_ZEND; i += 512) ws[i] = 0.f;
    int k = tid;
    float s = 0.f;
    #pragma unroll
    for (int d = 0; d < DIM; ++d) { float v = emb[k*DIM + d]; s += v*v; }
    ws[W_C + k] = s;
    float m = emaM[k];
    #pragma unroll
    for (int off = 32; off >= 1; off >>= 1) m += __shfl_down(m, off, 64);
    if ((tid & 63) == 0) ws[W_SUMM8 + (tid >> 6)] = m;
}

// Best-measured assign (r15/r19: 133us, VGPR 100, WRITE 544KB, conflicts 0,
// VALUBusy ~68%): register-tiled fp32 GEMM, 128 pts x 512 cw per block,
// 8x8 microtile, LDS-staged X and E, strict-< thread-local scan.
// Bracketing experiments all regressed: r16 dim-phasing, r17 loss-fold
// (false sharing), r18 half-tile, r20 global-E occupancy-4 (acc spill at
// the 64-VGPR cap), r10-r13 MFMA (compiler scratch pathology).
__global__ __launch_bounds__(256, 2) void assign_kernel(
    const float* __restrict__ enc, const float* __restrict__ emb,
    float* __restrict__ out, float* __restrict__ ws)
{
    __shared__ float XL[128*XPAD];   // [point][d]
    __shared__ float EL[128*EPAD];   // [cw][d]
    __shared__ float cnT[128];
    __shared__ int   bestI[128];

    const int t  = threadIdx.x;
    const int tx = t & 15;
    const int ty = t >> 4;
    const int wv = t >> 6, w = t & 63;
    const int R0 = blockIdx.x * 2;

    #pragma unroll
    for (int r2 = 0; r2 < 2; ++r2) {
        int R = R0 + r2, b = R >> 6, h = R & 63;
        const float* base = enc + (size_t)b*64*HW + (size_t)h*64 + w;
        int p = r2*64 + w;
        #pragma unroll
        for (int it = 0; it < 4; ++it) {
            int d0 = (it*4 + wv)*4;
            float4 v = make_float4(base[(size_t)(d0+0)*HW], base[(size_t)(d0+1)*HW],
                                   base[(size_t)(d0+2)*HW], base[(size_t)(d0+3)*HW]);
            *(float4*)(&XL[p*XPAD + d0]) = v;
        }
    }

    float best[8]; int bidx[8];
    #pragma unroll
    for (int i = 0; i < 8; ++i) { best[i] = 3.402823466e38f; bidx[i] = 0; }

    for (int tile = 0; tile < 4; ++tile) {
        __syncthreads();             // prior tile's EL reads done
        const float* esrc = emb + (size_t)tile*128*64;
        #pragma unroll
        for (int it = 0; it < 8; ++it) {
            int idx = t + it*256;
            *(float4*)(&EL[(idx >> 4)*EPAD + (idx & 15)*4]) =
                *(const float4*)(esrc + (idx >> 4)*64 + (idx & 15)*4);
        }
        if (t < 128) cnT[t] = ws[W_C + tile*128 + t];
        __syncthreads();

        float acc[8][8];
        #pragma unroll
        for (int i = 0; i < 8; ++i)
            #pragma unroll
            for (int j = 0; j < 8; ++j) acc[i][j] = 0.f;

        for (int c = 0; c < 16; ++c) {
            float4 xf[8], ef[8];
            #pragma unroll
            for (int i = 0; i < 8; ++i) {    // 4-address broadcast reads
                int p = 2*ty + (i&1) + 32*(i>>1);
                xf[i] = *(const float4*)(&XL[p*XPAD + c*4]);
            }
            #pragma unroll
            for (int j = 0; j < 8; ++j) {    // 2-way on bank quads = free
                int r = tx + 16*j;
                ef[j] = *(const float4*)(&EL[r*EPAD + c*4]);
            }
            #pragma unroll
            for (int i = 0; i < 8; ++i)
                #pragma unroll
                for (int j = 0; j < 8; ++j) {
                    acc[i][j] = fmaf(xf[i].x, ef[j].x, acc[i][j]);
                    acc[i][j] = fmaf(xf[i].y, ef[j].y, acc[i][j]);
                    acc[i][j] = fmaf(xf[i].z, ef[j].z, acc[i][j]);
                    acc[i][j] = fmaf(xf[i].w, ef[j].w, acc[i][j]);
                }
        }

        #pragma unroll
        for (int j = 0; j < 8; ++j) {
            int k = tile*128 + tx + 16*j;
            float cn = cnT[tx + 16*j];
            #pragma unroll
            for (int i = 0; i < 8; ++i) {
                float s = cn - 2.f*acc[i][j];
                if (s < best[i]) { best[i] = s; bidx[i] = k; }  // k strictly
            }                                                   // increasing
        }
    }

    // cross-lane argmin over the 16 tx-lanes sharing each point
    #pragma unroll
    for (int i = 0; i < 8; ++i) {
        float b = best[i]; int kx = bidx[i];
        #pragma unroll
        for (int off = 1; off < 16; off <<= 1) {
            float ob = __shfl_xor(b, off, 64);
            int   ok = __shfl_xor(kx, off, 64);
            if (ob < b || (ob == b && ok < kx)) { b = ob; kx = ok; }
        }
        if (tx == 0) bestI[2*ty + (i&1) + 32*(i>>1)] = kx;
    }
    __syncthreads();
    if (t < 128) out[O_IDX + (size_t)R0*64 + t] = (float)bestI[t];
}

// scatter v3 (best measured): role-split 16-wave kernel with per-wave dim
// rotation; loss computed inline in gather waves.
__global__ __launch_bounds__(1024, 1) void scatter_kernel(
    const float* __restrict__ enc, const float* __restrict__ emb,
    float* __restrict__ out, float* __restrict__ ws)
{
    __shared__ float dmL[KCODES][DIM+1];
    __shared__ float cntL[KCODES];
    __shared__ float redL[16];

    const int t  = threadIdx.x;
    const int w  = t & 63;
    const int wv = t >> 6;           // 0..15
    const int rw = wv & 7;           // row slot
    const int role = wv >> 3;        // 0: accumulate, 1: gather/store/loss
    const int pg = w >> 4, dl = w & 15;
    const int drot = (wv & 7) * 8;   // per-wave dim rotation (bijection)

    float* dmf = &dmL[0][0];
    for (int i = t; i < KCODES*(DIM+1); i += 1024) dmf[i] = 0.f;
    if (t < KCODES) cntL[t] = 0.f;
    __syncthreads();

    const int R = blockIdx.x * 8 + rw;
    const int b = R >> 6, h = R & 63;
    const float* base  = enc + (size_t)b*(64*HW) + (size_t)h*64;
    float*       obase = out + O_OUT + (size_t)b*(64*HW) + (size_t)h*64;

    const int bidx = (int)out[O_IDX + (size_t)R*64 + w];
    float lsum = 0.f;

    if (role == 0) {
        atomicAdd(&cntL[bidx], 1.0f);
        #pragma unroll
        for (int c = 0; c < 4; ++c) {
            #pragma unroll
            for (int jj = 0; jj < 16; ++jj) {
                int p  = jj*4 + pg;
                int kb = __shfl(bidx, p, 64);
                int d  = (c*16 + dl + drot) & 63;
                atomicAdd(&dmL[kb][d], base[(size_t)d*HW + p]);
            }
        }
    } else {
        #pragma unroll
        for (int c = 0; c < 4; ++c) {
            #pragma unroll
            for (int jj = 0; jj < 16; ++jj) {
                int p  = jj*4 + pg;
                int kb = __shfl(bidx, p, 64);
                int d  = (c*16 + dl + drot) & 63;
                float xv = base[(size_t)d*HW + p];
                float q  = emb[kb*64 + d];
                obase[(size_t)d*HW + p] = q;
                float df = q - xv;
                lsum = fmaf(df, df, lsum);
            }
        }
    }

    #pragma unroll
    for (int off = 32; off >= 1; off >>= 1) lsum += __shfl_down(lsum, off, 64);
    if (w == 0) redL[wv] = lsum;
    __syncthreads();
    if (t == 0) {
        float s = 0.f;
        #pragma unroll
        for (int v = 8; v < 16; ++v) s += redL[v];
        atomicAdd(&ws[W_LOSS], s);
    }

    // flush: wave wv owns 32 rows; lane = dim (coalesced 256B atomic runs)
    for (int k = wv*32; k < wv*32 + 32; ++k) {
        float c = cntL[k];
        if (c == 0.f) continue;
        atomicAdd(&ws[W_DM + k*64 + w], dmL[k][w]);
        if (w == 0) atomicAdd(&ws[W_CNT + k], c);
    }
}

// Single fully-parallel finalize; Ntot from the 8 deterministic partials.
__global__ void finalize_kernel(const float* __restrict__ emam,
                                const float* __restrict__ emaM,
                                float* __restrict__ out,
                                const float* __restrict__ ws)
{
    int i = blockIdx.x * blockDim.x + threadIdx.x;  // 0..32767
    int k = i >> 6;
    float summ = 0.f;
    #pragma unroll
    for (int v = 0; v < 8; ++v) summ += ws[W_SUMM8 + v];
    float Ntot = 0.99f * summ + 0.01f * (float)NPTS;
    float nM = 0.99f * emaM[k] + 0.01f * ws[W_CNT + k];
    float sm = (nM + 1e-5f) / (Ntot + 1e-5f * (float)KCODES) * Ntot;
    float nm = 0.99f * emam[i] + 0.01f * ws[W_DM + i];
    out[O_M + i] = nm;
    out[O_EMB + i] = nm / sm;
    if ((i & 63) == 0) out[O_MM + k] = sm;
    if (i == 0) out[O_LOSS] = 0.25f * ws[W_LOSS] / (float)((size_t)NPTS * DIM);
}

extern "C" void kernel_launch(void* const* d_in, const int* in_sizes, int n_in,
                              void* d_out, int out_size, void* d_ws, size_t ws_size,
                              hipStream_t stream)
{
    const float* enc  = (const float*)d_in[0];
    const float* emb  = (const float*)d_in[1];
    const float* emam = (const float*)d_in[2];
    const float* emaM = (const float*)d_in[3];
    float* out = (float*)d_out;
    float* ws  = (float*)d_ws;

    cnorm_kernel<<<2, 256, 0, stream>>>(emb, emaM, ws);   // zeroes ws too
    assign_kernel<<<NPTS/128, 256, 0, stream>>>(enc, emb, out, ws);   // 1024 blocks
    scatter_kernel<<<256, 1024, 0, stream>>>(enc, emb, out, ws);      // 8 rows/blk
    finalize_kernel<<<(KCODES*DIM)/256, 256, 0, stream>>>(emam, emaM, out, ws);
}